// Round 2
// baseline (202.385 us; speedup 1.0000x reference)
//
#include <hip/hip_runtime.h>

#define HH  512
#define WW  512
#define RAD 10
#define KK  21
#define SEG 16                  // rows per segment (LDS buffer holds one segment)
#define SEGS 4                  // segments per block -> 64 output rows/block
#define NROWS (SEG + 2 * RAD)   // 36 raw rows live in the register ring
#define LSTRIDE 540             // LDS row stride (floats): 532 used, 16B-aligned

// Fused separable Gaussian blur (21x21, sigma=3), reflect padding.
// v3: software-pipelined 4-segment blocks.
//   - Per segment: issue the 16 NEW raw-row loads -> run horizontal pass of
//     the PREVIOUS segment (~800cy FMA hides load latency) -> barrier ->
//     vertical-blur next segment into LDS -> barrier.
//   - 20-row segment overlap kept in a statically-indexed register ring
//     (rows[36], shift 20 v_movs/seg): loads/thread 144 -> 84 (halo 2.25x->1.31x).
//   - Both convs are consume-on-arrival scatter form (acc[o] += wt[i-o]*v):
//     first FMA depends on the FIRST load, not the 21st.
//   - 768 blocks = exactly 3/CU (perfect balance), XCD-bijective remap.
//   - __launch_bounds__(512,6): <=85 VGPR -> 24 waves/CU resident.
__global__ __launch_bounds__(512, 6) void gauss_blur_kernel(
    const float* __restrict__ x, float* __restrict__ out)
{
    // g[d] = exp(-d^2/18), w = g/sum(g); 2D kernel = outer(w,w) exactly.
    const float wt[KK] = {
        0.00051432f, 0.00147793f, 0.00380033f, 0.00874446f, 0.01800488f,
        0.03317359f, 0.05469399f, 0.08069227f, 0.10652936f, 0.12584957f,
        0.13303907f,
        0.12584957f, 0.10652936f, 0.08069227f, 0.05469399f, 0.03317359f,
        0.01800488f, 0.00874446f, 0.00380033f, 0.00147793f, 0.00051432f
    };

    __shared__ __align__(16) float vbuf[SEG * LSTRIDE];   // 34.56 KB

    // XCD-contiguous bijective remap: 768 blocks % 8 == 0.
    const int bid = blockIdx.y * gridDim.x + blockIdx.x;
    const int cpx = (gridDim.x * gridDim.y) >> 3;          // 96
    const int lid = (bid & 7) * cpx + (bid >> 3);
    const int y0  = (lid & 7) * (SEG * SEGS);              // gridDim.x == 8
    const int img = lid >> 3;

    const int t = threadIdx.x;                             // 0..511 = column

    const float* xim = x   + (size_t)img * (HH * WW);
    float*       oim = out + (size_t)img * (HH * WW);

    float rows[NROWS];           // register ring of raw rows (static indices only)

    // ---------------- prologue: 36 loads + vertical blur of segment 0 -------
    #pragma unroll
    for (int i = 0; i < NROWS; ++i) {
        int r  = y0 - RAD + i;
        int rr = r < 0 ? -r : (r > HH - 1 ? 2 * (HH - 1) - r : r);
        rows[i] = xim[rr * WW + t];
    }
    {
        float acc[SEG];
        #pragma unroll
        for (int r = 0; r < SEG; ++r) acc[r] = 0.f;
        #pragma unroll
        for (int i = 0; i < NROWS; ++i) {      // consume rows in arrival order
            const int lo = (i - 2 * RAD) < 0 ? 0 : (i - 2 * RAD);
            const int hi = i < (SEG - 1) ? i : (SEG - 1);
            #pragma unroll
            for (int r = lo; r <= hi; ++r)
                acc[r] = fmaf(wt[i - r], rows[i], acc[r]);
        }
        #pragma unroll
        for (int r = 0; r < SEG; ++r) {
            float* vb = vbuf + r * LSTRIDE;
            vb[RAD + t] = acc[r];
            if (t >= 1 && t <= RAD)               vb[RAD - t] = acc[r];
            if (t >= WW - 1 - RAD && t <= WW - 2) vb[RAD + 2 * (WW - 1) - t] = acc[r];
        }
    }
    #pragma unroll
    for (int i = 0; i < NROWS - SEG; ++i) rows[i] = rows[i + SEG];  // ring shift
    __syncthreads();

    // ---------------- segment loop ------------------------------------------
    for (int s = 0; s < SEGS; ++s) {
        // (1) issue the 16 new raw-row loads for segment s+1 (hidden by (2))
        if (s + 1 < SEGS) {
            #pragma unroll
            for (int i = 0; i < SEG; ++i) {
                int r  = y0 + SEG * (s + 1) - RAD + (NROWS - SEG) + i;
                int rr = r < 0 ? -r : (r > HH - 1 ? 2 * (HH - 1) - r : r);
                rows[(NROWS - SEG) + i] = xim[rr * WW + t];
            }
        }

        // (2) horizontal blur of segment s from LDS + store
        {
            const int r = t & (SEG - 1);
            const int q = t >> 4;                          // 0..31
            // padded window start = q*16 -> 16B aligned
            const float* vr = vbuf + r * LSTRIDE + q * 16;

            float acc[16];
            #pragma unroll
            for (int j = 0; j < 16; ++j) acc[j] = 0.f;

            #pragma unroll
            for (int j = 0; j < 9; ++j) {                  // 9x ds_read_b128
                const float4 v4 = *(const float4*)(vr + 4 * j);
                const float va[4] = { v4.x, v4.y, v4.z, v4.w };
                #pragma unroll
                for (int e = 0; e < 4; ++e) {              // scatter-accumulate
                    const int i  = 4 * j + e;
                    const int lo = (i - 2 * RAD) < 0 ? 0 : (i - 2 * RAD);
                    const int hi = i < 15 ? i : 15;
                    #pragma unroll
                    for (int o = lo; o <= hi; ++o)
                        acc[o] = fmaf(wt[i - o], va[e], acc[o]);
                }
            }

            float* op = oim + (size_t)(y0 + SEG * s + r) * WW + q * 16;
            #pragma unroll
            for (int j = 0; j < 4; ++j)
                *(float4*)(op + 4 * j) =
                    make_float4(acc[4*j], acc[4*j+1], acc[4*j+2], acc[4*j+3]);
        }

        // (3..6) vertical blur of segment s+1 into the same LDS buffer
        if (s + 1 < SEGS) {
            __syncthreads();                               // vbuf reads done

            float acc[SEG];
            #pragma unroll
            for (int r = 0; r < SEG; ++r) acc[r] = 0.f;
            #pragma unroll
            for (int i = 0; i < NROWS; ++i) {              // waits vmcnt per row
                const int lo = (i - 2 * RAD) < 0 ? 0 : (i - 2 * RAD);
                const int hi = i < (SEG - 1) ? i : (SEG - 1);
                #pragma unroll
                for (int r = lo; r <= hi; ++r)
                    acc[r] = fmaf(wt[i - r], rows[i], acc[r]);
            }
            #pragma unroll
            for (int r = 0; r < SEG; ++r) {
                float* vb = vbuf + r * LSTRIDE;
                vb[RAD + t] = acc[r];
                if (t >= 1 && t <= RAD)               vb[RAD - t] = acc[r];
                if (t >= WW - 1 - RAD && t <= WW - 2) vb[RAD + 2 * (WW - 1) - t] = acc[r];
            }
            #pragma unroll
            for (int i = 0; i < NROWS - SEG; ++i) rows[i] = rows[i + SEG];
            __syncthreads();                               // vbuf ready
        }
    }
}

extern "C" void kernel_launch(void* const* d_in, const int* in_sizes, int n_in,
                              void* d_out, int out_size, void* d_ws, size_t ws_size,
                              hipStream_t stream) {
    const float* x = (const float*)d_in[0];
    float* out = (float*)d_out;
    const int n_img = in_sizes[0] / (HH * WW);     // 32*3 = 96
    dim3 grid(HH / (SEG * SEGS), n_img);           // (8, 96) = 768 blocks
    gauss_blur_kernel<<<grid, dim3(512), 0, stream>>>(x, out);
}